// Round 19
// baseline (294.359 us; speedup 1.0000x reference)
//
#include <hip/hip_runtime.h>
#include <hip/hip_bf16.h>
#include <math.h>

#define NPART 8   // s-blocks of 512 (2 chunks of 256): 64x8 = 512 blocks = 2/CU

typedef __attribute__((ext_vector_type(8))) short bf16x8;  // MFMA A/B frag (4 VGPR)
typedef __attribute__((ext_vector_type(4))) float f32x4;   // MFMA C/D frag

static __device__ inline ushort f2bf(float x) {
  __hip_bfloat16 h = __float2bfloat16(x);
  return *reinterpret_cast<ushort*>(&h);
}
static __device__ inline float bf2f(ushort u) {
  uint x = ((uint)u) << 16;
  return *reinterpret_cast<float*>(&x);
}

// ---------------------------------------------------------------------------
// Fused dual cast f32 -> bf16 (support + query in one dispatch)
// ---------------------------------------------------------------------------
__global__ __launch_bounds__(256) void cast2_bf16_kernel(
    const float* __restrict__ a, ushort* __restrict__ oa, size_t n4a,
    const float* __restrict__ b, ushort* __restrict__ ob, size_t n4b) {
  size_t i = (size_t)blockIdx.x * blockDim.x + threadIdx.x;
  size_t stride = (size_t)gridDim.x * blockDim.x;
  for (; i < n4a + n4b; i += stride) {
    const float4* src = (i < n4a) ? &((const float4*)a)[i]
                                  : &((const float4*)b)[i - n4a];
    ushort4* dst = (i < n4a) ? &((ushort4*)oa)[i] : &((ushort4*)ob)[i - n4a];
    float4 v = *src;
    ushort4 u;
    u.x = f2bf(v.x); u.y = f2bf(v.y); u.z = f2bf(v.z); u.w = f2bf(v.w);
    *dst = u;
  }
}

// ---------------------------------------------------------------------------
__global__ __launch_bounds__(256) void transpose_cast_kernel(
    const float* __restrict__ W, ushort* __restrict__ Wt, int K, int D) {
  __shared__ float t[64][65];
  const int k0 = blockIdx.x * 64, d0 = blockIdx.y * 64;
  const int r = threadIdx.x >> 6, c = threadIdx.x & 63;
#pragma unroll
  for (int i = 0; i < 16; i++)
    t[r + i * 4][c] = W[(size_t)(k0 + r + i * 4) * D + d0 + c];
  __syncthreads();
#pragma unroll
  for (int i = 0; i < 16; i++)
    Wt[(size_t)(d0 + r + i * 4) * K + k0 + c] = f2bf(t[c][r + i * 4]);
}

// ---------------------------------------------------------------------------
// FUSED encoder GEMM — r16-proven best config (unchanged from r18): 512 thr
// (8 waves 2x4), tile 128x256, grid (96,2)=192 blocks, 3-deep counted-vmcnt.
// ---------------------------------------------------------------------------
#define ESTAGE(kt, pb)                                                        \
  {                                                                           \
    _Pragma("unroll")                                                         \
    for (int i_ = 0; i_ < 3; i_++) {                                          \
      const int seg_ = wave * 3 + i_;                                         \
      const ushort* src_ = (seg_ < 8)                                         \
          ? Xall + (row0 + seg_ * 16 + fr) * (size_t)K + (kt) * 32 + kg * 8   \
          : Wt + (d0 + (seg_ - 8) * 16 + fr) * (size_t)K + (kt) * 32 + kg * 8;\
      __builtin_amdgcn_global_load_lds(                                       \
          (const __attribute__((address_space(1))) void*)src_,                \
          (__attribute__((address_space(3))) void*)                           \
              &tile[(pb) * 12288 + seg_ * 512 + lane * 8],                    \
          16, 0, 0);                                                          \
    }                                                                         \
  }

__global__ __launch_bounds__(512, 4) void encode_mfma_kernel(
    const ushort* __restrict__ Xall, const ushort* __restrict__ Wt,
    const float* __restrict__ bias, float* __restrict__ emb,
    int K, int D) {
  __shared__ ushort tile[3 * 12288];   // 72 KB, 3-deep rotation
  const int tid = threadIdx.x;
  const int wave = tid >> 6, lane = tid & 63;
  const int fr = lane & 15, kg = lane >> 4;
  const int wr = wave >> 2, wc = wave & 3;
  const long row0 = (long)blockIdx.x * 128;
  const int d0 = blockIdx.y * 256;

  f32x4 acc[4][4];
#pragma unroll
  for (int rg = 0; rg < 4; rg++)
#pragma unroll
    for (int cg = 0; cg < 4; cg++) acc[rg][cg] = (f32x4){0.f, 0.f, 0.f, 0.f};

  ESTAGE(0, 0)
  ESTAGE(1, 1)
  int bcur = 0;
  for (int t = 0; t < 32; t++) {     // K = 1024 = 32 x BK(32)
    if (t < 31) asm volatile("s_waitcnt vmcnt(3)" ::: "memory");
    else        asm volatile("s_waitcnt vmcnt(0)" ::: "memory");
    __builtin_amdgcn_sched_barrier(0);
    __builtin_amdgcn_s_barrier();
    if (t < 30) {
      int bnext = bcur + 2; if (bnext >= 3) bnext -= 3;
      ESTAGE(t + 2, bnext)
    }
    const ushort* base = &tile[bcur * 12288];
    bf16x8 bfr[4];
#pragma unroll
    for (int cg = 0; cg < 4; cg++)
      bfr[cg] = *(const bf16x8*)&base[(8 + wc * 4 + cg) * 512 + lane * 8];
#pragma unroll
    for (int rg = 0; rg < 4; rg++) {
      bf16x8 af = *(const bf16x8*)&base[(wr * 4 + rg) * 512 + lane * 8];
#pragma unroll
      for (int cg = 0; cg < 4; cg++)
        acc[rg][cg] = __builtin_amdgcn_mfma_f32_16x16x32_bf16(
            af, bfr[cg], acc[rg][cg], 0, 0, 0);
    }
    bcur++; if (bcur == 3) bcur = 0;
  }
#pragma unroll
  for (int cg = 0; cg < 4; cg++) {
    const int col = d0 + wc * 64 + cg * 16 + fr;
    const float bl = bias[col];
#pragma unroll
    for (int rg = 0; rg < 4; rg++)
#pragma unroll
      for (int r = 0; r < 4; r++)
        emb[(row0 + wr * 64 + rg * 16 + kg * 4 + r) * (size_t)D + col] =
            acc[rg][cg][r] + bl;
  }
}

// ---------------------------------------------------------------------------
__global__ __launch_bounds__(256) void norm_bf16_kernel(
    const float* __restrict__ in, ushort* __restrict__ outb, int nrows, int D) {
  int row = (int)((blockIdx.x * blockDim.x + threadIdx.x) >> 6);
  int lane = threadIdx.x & 63;
  if (row >= nrows) return;
  const float4* p = (const float4*)(in + (size_t)row * D);
  float4 v0 = p[lane];
  float4 v1 = p[lane + 64];
  float ss = v0.x * v0.x + v0.y * v0.y + v0.z * v0.z + v0.w * v0.w
           + v1.x * v1.x + v1.y * v1.y + v1.z * v1.z + v1.w * v1.w;
#pragma unroll
  for (int off = 32; off > 0; off >>= 1) ss += __shfl_xor(ss, off);
  float inv = 1.0f / fmaxf(sqrtf(ss), 1e-12f);
  ushort4 u0, u1;
  u0.x = f2bf(v0.x * inv); u0.y = f2bf(v0.y * inv);
  u0.z = f2bf(v0.z * inv); u0.w = f2bf(v0.w * inv);
  u1.x = f2bf(v1.x * inv); u1.y = f2bf(v1.y * inv);
  u1.z = f2bf(v1.z * inv); u1.w = f2bf(v1.w * inv);
  ushort* o = outb + (size_t)row * D;
  *(ushort4*)(o + 4 * lane) = u0;
  *(ushort4*)(o + 256 + 4 * lane) = u1;
}

// ---------------------------------------------------------------------------
// MFMA attention: per block, TWO sequential 256-support chunks (NPART=8),
// accumulating acc2 across chunks. Per-chunk phases byte-identical to r18:
// 3-deep counted-vmcnt phase-1, exp->bf16 swizzled P, P @ onehot MFMA.
// Chunk-loop safety: top-of-chunk __syncthreads — each wave arrives only
// after its phase-3 MFMAs issued (lgkmcnt drained => P/lab reads complete),
// so restaging over P and overwriting lab is safe.
// ---------------------------------------------------------------------------
#define STAGE_BODY(kt, pb)                                                    \
  {                                                                           \
    _Pragma("unroll")                                                         \
    for (int i_ = 0; i_ < 3; i_++) {                                          \
      const int seg_ = wave * 3 + i_;                                         \
      const ushort* src_ = (seg_ < 8)                                         \
          ? Qb + (q0 + seg_ * 16 + fr) * (size_t)D + (kt) * 32 + kg * 8       \
          : Sb + (s0 + (seg_ - 8) * 16 + fr) * (size_t)D + (kt) * 32 + kg * 8;\
      __builtin_amdgcn_global_load_lds(                                       \
          (const __attribute__((address_space(1))) void*)src_,                \
          (__attribute__((address_space(3))) void*)                           \
              &tile[(pb) * 12288 + seg_ * 512 + lane * 8],                    \
          16, 0, 0);                                                          \
    }                                                                         \
  }

__global__ __launch_bounds__(512, 4) void attn_mfma_kernel(
    const ushort* __restrict__ Qb, const ushort* __restrict__ Sb,
    const int* __restrict__ labels, ushort* __restrict__ partial,
    int nq, int D) {
  __shared__ ushort tile[3 * 12288];  // staging rotation; P[128][256] overlays
  __shared__ int lab[256];
  const int tid = threadIdx.x;
  const int wave = tid >> 6, lane = tid & 63;
  const int fr = lane & 15, kg = lane >> 4;
  const int wr = wave >> 2, wc = wave & 3;
  const long q0 = (long)blockIdx.x * 128;
  const int part = blockIdx.y;
  const int cls = wc * 16 + fr;

  f32x4 acc2[4];
#pragma unroll
  for (int rg = 0; rg < 4; rg++) acc2[rg] = (f32x4){0.f, 0.f, 0.f, 0.f};

  for (int chunk = 0; chunk < 2; chunk++) {
    const long s0 = (long)part * 512 + chunk * 256;
    __syncthreads();                  // prev chunk's P/lab reads complete
    if (tid < 256) lab[tid] = labels[s0 + tid];

    f32x4 acc[4][4];
#pragma unroll
    for (int rg = 0; rg < 4; rg++)
#pragma unroll
      for (int cg = 0; cg < 4; cg++) acc[rg][cg] = (f32x4){0.f, 0.f, 0.f, 0.f};

    // ---- phase 1: score GEMM, 3-deep counted-vmcnt pipeline ----
    STAGE_BODY(0, 0)
    STAGE_BODY(1, 1)
    int bcur = 0;
    for (int t = 0; t < 16; t++) {
      if (t < 15) asm volatile("s_waitcnt vmcnt(3)" ::: "memory");
      else        asm volatile("s_waitcnt vmcnt(0)" ::: "memory");
      __builtin_amdgcn_sched_barrier(0);
      __builtin_amdgcn_s_barrier();
      if (t < 14) {
        int bnext = bcur + 2; if (bnext >= 3) bnext -= 3;
        STAGE_BODY(t + 2, bnext)
      }
      const ushort* base = &tile[bcur * 12288];
      bf16x8 bfr[4];
#pragma unroll
      for (int cg = 0; cg < 4; cg++)
        bfr[cg] = *(const bf16x8*)&base[(8 + wc * 4 + cg) * 512 + lane * 8];
#pragma unroll
      for (int rg = 0; rg < 4; rg++) {
        bf16x8 af = *(const bf16x8*)&base[(wr * 4 + rg) * 512 + lane * 8];
#pragma unroll
        for (int cg = 0; cg < 4; cg++)
          acc[rg][cg] = __builtin_amdgcn_mfma_f32_16x16x32_bf16(
              af, bfr[cg], acc[rg][cg], 0, 0, 0);
      }
      bcur++; if (bcur == 3) bcur = 0;
    }

    // ---- phase 2: P = exp(S) bf16 -> swizzled LDS ----
    __syncthreads();
#pragma unroll
    for (int rg = 0; rg < 4; rg++)
#pragma unroll
      for (int cg = 0; cg < 4; cg++)
#pragma unroll
        for (int r = 0; r < 4; r++) {
          const int q  = wr * 64 + rg * 16 + kg * 4 + r;
          const int sc = wc * 64 + cg * 16 + fr;
          const int byteoff = ((q << 9) + (sc << 1)) ^ ((q & 7) << 4);
          *(ushort*)((char*)tile + byteoff) = f2bf(__expf(acc[rg][cg][r]));
        }
    __syncthreads();

    // ---- phase 3: acc2 += P @ onehot, K=256 (8 k-steps) ----
#pragma unroll
    for (int t = 0; t < 8; t++) {
      const int kb = t * 32 + kg * 8;
      int4 l0 = *(const int4*)&lab[kb];
      int4 l1 = *(const int4*)&lab[kb + 4];
      uint b0 = ((l0.x == cls) ? 0x3F80u : 0u) | (((l0.y == cls) ? 0x3F80u : 0u) << 16);
      uint b1 = ((l0.z == cls) ? 0x3F80u : 0u) | (((l0.w == cls) ? 0x3F80u : 0u) << 16);
      uint b2 = ((l1.x == cls) ? 0x3F80u : 0u) | (((l1.y == cls) ? 0x3F80u : 0u) << 16);
      uint b3 = ((l1.z == cls) ? 0x3F80u : 0u) | (((l1.w == cls) ? 0x3F80u : 0u) << 16);
      uint4 bu = {b0, b1, b2, b3};
      bf16x8 bfr = *(bf16x8*)&bu;
#pragma unroll
      for (int rg = 0; rg < 4; rg++) {
        const int qrow = wr * 64 + rg * 16 + fr;
        const int byteoff = ((qrow << 9) + (kb << 1)) ^ ((qrow & 7) << 4);
        bf16x8 af = *(const bf16x8*)((char*)tile + byteoff);
        acc2[rg] = __builtin_amdgcn_mfma_f32_16x16x32_bf16(af, bfr, acc2[rg], 0, 0, 0);
      }
    }
  }

  // ---- store bf16 partial (sums over this part's 512 supports) ----
#pragma unroll
  for (int rg = 0; rg < 4; rg++)
#pragma unroll
    for (int r = 0; r < 4; r++) {
      const long q = q0 + wr * 64 + rg * 16 + kg * 4 + r;
      partial[((size_t)part * nq + q) * 64 + cls] = f2bf(acc2[rg][r]);
    }
}

// ---------------------------------------------------------------------------
__global__ __launch_bounds__(256) void combine_kernel(
    const ushort* __restrict__ partial, float* __restrict__ out, int nq, int nsplit) {
  int q = (int)((blockIdx.x * blockDim.x + threadIdx.x) >> 6);
  int lane = threadIdx.x & 63;
  if (q >= nq) return;
  float v = 0.0f;
  for (int h = 0; h < nsplit; h++)
    v += bf2f(partial[((size_t)h * nq + q) * 64 + lane]);
  float s = v;
#pragma unroll
  for (int off = 32; off > 0; off >>= 1) s += __shfl_xor(s, off);
  out[(size_t)q * 64 + lane] = v / s;
}

// ---------------------------------------------------------------------------
// Workspace: [0,8M) xb_s  [8M,24M) xb_q   (contiguous 12288x1024 bf16)
// [24M,25M) Wt  [25M,33M) s_emb  [33M,49M) q_emb (contiguous 12288x512 f32)
// after encode+norm: s_bf [0,4M), q_bf [4M,12M) (contiguous 12288x512 bf16),
// partial (bf16, 8MB, NPART=8) [12M,20M) — aliases dead xb_q region.
// All regions rewritten every call; d_out fully overwritten by combine.
// ---------------------------------------------------------------------------
extern "C" void kernel_launch(void* const* d_in, const int* in_sizes, int n_in,
                              void* d_out, int out_size, void* d_ws, size_t ws_size,
                              hipStream_t stream) {
  const float* support = (const float*)d_in[0];
  const float* query   = (const float*)d_in[1];
  const float* W       = (const float*)d_in[2];
  const float* b       = (const float*)d_in[3];
  const int*   labels  = (const int*)d_in[4];

  const int d_dim    = in_sizes[3];            // 512
  const int in_dim   = in_sizes[2] / d_dim;    // 1024
  const int n_support = in_sizes[0] / in_dim;  // 4096
  const int n_query   = in_sizes[1] / in_dim;  // 8192
  const int n_all     = n_support + n_query;   // 12288

  char* base = (char*)d_ws;
  ushort* xb_s  = (ushort*)(base);                        // [0,8M) -- xb base
  ushort* xb_q  = (ushort*)(base + ((size_t)8 << 20));
  ushort* Wt    = (ushort*)(base + ((size_t)24 << 20));
  float*  s_emb = (float*)(base + ((size_t)25 << 20));    // emb base (24M B)
  float*  q_emb = (float*)(base + ((size_t)33 << 20));
  ushort* s_bf  = (ushort*)(base);                        // alias xb_s (dead)
  ushort* q_bf  = (ushort*)(base + ((size_t)4 << 20));    // alias xb (dead)
  ushort* partial = (ushort*)(base + ((size_t)12 << 20)); // alias xb_q (dead)

  dim3 blk(256);
  cast2_bf16_kernel<<<2048, blk, 0, stream>>>(
      support, xb_s, (size_t)n_support * in_dim / 4,
      query, xb_q, (size_t)n_query * in_dim / 4);
  transpose_cast_kernel<<<dim3(in_dim / 64, d_dim / 64), blk, 0, stream>>>(W, Wt, in_dim, d_dim);
  encode_mfma_kernel<<<dim3(n_all / 128, d_dim / 256), dim3(512), 0, stream>>>(
      xb_s, Wt, b, s_emb, in_dim, d_dim);
  norm_bf16_kernel<<<dim3(n_all / 4), blk, 0, stream>>>(s_emb, s_bf, n_all, d_dim);
  attn_mfma_kernel<<<dim3(n_query / 128, NPART), dim3(512), 0, stream>>>(
      q_bf, s_bf, labels, partial, n_query, d_dim);
  combine_kernel<<<dim3(n_query / 4), blk, 0, stream>>>(partial, (float*)d_out, n_query, NPART);
}

// Round 20
// 116.468 us; speedup vs baseline: 2.5274x; 2.5274x over previous
//
#include <hip/hip_runtime.h>
#include <hip/hip_bf16.h>
#include <math.h>

#define NPART 16  // s-blocks of 256: 64x16 = 1024 blocks (r18-proven)

typedef __attribute__((ext_vector_type(8))) short bf16x8;  // MFMA A/B frag (4 VGPR)
typedef __attribute__((ext_vector_type(4))) float f32x4;   // MFMA C/D frag

static __device__ inline ushort f2bf(float x) {
  __hip_bfloat16 h = __float2bfloat16(x);
  return *reinterpret_cast<ushort*>(&h);
}
static __device__ inline float bf2f(ushort u) {
  uint x = ((uint)u) << 16;
  return *reinterpret_cast<float*>(&x);
}

// ---------------------------------------------------------------------------
// Fused dual cast f32 -> bf16 (support + query in one dispatch; r19-keep)
// ---------------------------------------------------------------------------
__global__ __launch_bounds__(256) void cast2_bf16_kernel(
    const float* __restrict__ a, ushort* __restrict__ oa, size_t n4a,
    const float* __restrict__ b, ushort* __restrict__ ob, size_t n4b) {
  size_t i = (size_t)blockIdx.x * blockDim.x + threadIdx.x;
  size_t stride = (size_t)gridDim.x * blockDim.x;
  for (; i < n4a + n4b; i += stride) {
    const float4* src = (i < n4a) ? &((const float4*)a)[i]
                                  : &((const float4*)b)[i - n4a];
    ushort4* dst = (i < n4a) ? &((ushort4*)oa)[i] : &((ushort4*)ob)[i - n4a];
    float4 v = *src;
    ushort4 u;
    u.x = f2bf(v.x); u.y = f2bf(v.y); u.z = f2bf(v.z); u.w = f2bf(v.w);
    *dst = u;
  }
}

// ---------------------------------------------------------------------------
__global__ __launch_bounds__(256) void transpose_cast_kernel(
    const float* __restrict__ W, ushort* __restrict__ Wt, int K, int D) {
  __shared__ float t[64][65];
  const int k0 = blockIdx.x * 64, d0 = blockIdx.y * 64;
  const int r = threadIdx.x >> 6, c = threadIdx.x & 63;
#pragma unroll
  for (int i = 0; i < 16; i++)
    t[r + i * 4][c] = W[(size_t)(k0 + r + i * 4) * D + d0 + c];
  __syncthreads();
#pragma unroll
  for (int i = 0; i < 16; i++)
    Wt[(size_t)(d0 + r + i * 4) * K + k0 + c] = f2bf(t[c][r + i * 4]);
}

// ---------------------------------------------------------------------------
// FUSED encoder GEMM — r16-proven best config: 512 thr (8 waves 2x4),
// tile 128x256, grid (96,2)=192 blocks, 3-deep counted-vmcnt rotation.
// ---------------------------------------------------------------------------
#define ESTAGE(kt, pb)                                                        \
  {                                                                           \
    _Pragma("unroll")                                                         \
    for (int i_ = 0; i_ < 3; i_++) {                                          \
      const int seg_ = wave * 3 + i_;                                         \
      const ushort* src_ = (seg_ < 8)                                         \
          ? Xall + (row0 + seg_ * 16 + fr) * (size_t)K + (kt) * 32 + kg * 8   \
          : Wt + (d0 + (seg_ - 8) * 16 + fr) * (size_t)K + (kt) * 32 + kg * 8;\
      __builtin_amdgcn_global_load_lds(                                       \
          (const __attribute__((address_space(1))) void*)src_,                \
          (__attribute__((address_space(3))) void*)                           \
              &tile[(pb) * 12288 + seg_ * 512 + lane * 8],                    \
          16, 0, 0);                                                          \
    }                                                                         \
  }

__global__ __launch_bounds__(512, 4) void encode_mfma_kernel(
    const ushort* __restrict__ Xall, const ushort* __restrict__ Wt,
    const float* __restrict__ bias, float* __restrict__ emb,
    int K, int D) {
  __shared__ ushort tile[3 * 12288];   // 72 KB, 3-deep rotation
  const int tid = threadIdx.x;
  const int wave = tid >> 6, lane = tid & 63;
  const int fr = lane & 15, kg = lane >> 4;
  const int wr = wave >> 2, wc = wave & 3;
  const long row0 = (long)blockIdx.x * 128;
  const int d0 = blockIdx.y * 256;

  f32x4 acc[4][4];
#pragma unroll
  for (int rg = 0; rg < 4; rg++)
#pragma unroll
    for (int cg = 0; cg < 4; cg++) acc[rg][cg] = (f32x4){0.f, 0.f, 0.f, 0.f};

  ESTAGE(0, 0)
  ESTAGE(1, 1)
  int bcur = 0;
  for (int t = 0; t < 32; t++) {     // K = 1024 = 32 x BK(32)
    if (t < 31) asm volatile("s_waitcnt vmcnt(3)" ::: "memory");
    else        asm volatile("s_waitcnt vmcnt(0)" ::: "memory");
    __builtin_amdgcn_sched_barrier(0);
    __builtin_amdgcn_s_barrier();
    if (t < 30) {
      int bnext = bcur + 2; if (bnext >= 3) bnext -= 3;
      ESTAGE(t + 2, bnext)
    }
    const ushort* base = &tile[bcur * 12288];
    bf16x8 bfr[4];
#pragma unroll
    for (int cg = 0; cg < 4; cg++)
      bfr[cg] = *(const bf16x8*)&base[(8 + wc * 4 + cg) * 512 + lane * 8];
#pragma unroll
    for (int rg = 0; rg < 4; rg++) {
      bf16x8 af = *(const bf16x8*)&base[(wr * 4 + rg) * 512 + lane * 8];
#pragma unroll
      for (int cg = 0; cg < 4; cg++)
        acc[rg][cg] = __builtin_amdgcn_mfma_f32_16x16x32_bf16(
            af, bfr[cg], acc[rg][cg], 0, 0, 0);
    }
    bcur++; if (bcur == 3) bcur = 0;
  }
#pragma unroll
  for (int cg = 0; cg < 4; cg++) {
    const int col = d0 + wc * 64 + cg * 16 + fr;
    const float bl = bias[col];
#pragma unroll
    for (int rg = 0; rg < 4; rg++)
#pragma unroll
      for (int r = 0; r < 4; r++)
        emb[(row0 + wr * 64 + rg * 16 + kg * 4 + r) * (size_t)D + col] =
            acc[rg][cg][r] + bl;
  }
}

// ---------------------------------------------------------------------------
__global__ __launch_bounds__(256) void norm_bf16_kernel(
    const float* __restrict__ in, ushort* __restrict__ outb, int nrows, int D) {
  int row = (int)((blockIdx.x * blockDim.x + threadIdx.x) >> 6);
  int lane = threadIdx.x & 63;
  if (row >= nrows) return;
  const float4* p = (const float4*)(in + (size_t)row * D);
  float4 v0 = p[lane];
  float4 v1 = p[lane + 64];
  float ss = v0.x * v0.x + v0.y * v0.y + v0.z * v0.z + v0.w * v0.w
           + v1.x * v1.x + v1.y * v1.y + v1.z * v1.z + v1.w * v1.w;
#pragma unroll
  for (int off = 32; off > 0; off >>= 1) ss += __shfl_xor(ss, off);
  float inv = 1.0f / fmaxf(sqrtf(ss), 1e-12f);
  ushort4 u0, u1;
  u0.x = f2bf(v0.x * inv); u0.y = f2bf(v0.y * inv);
  u0.z = f2bf(v0.z * inv); u0.w = f2bf(v0.w * inv);
  u1.x = f2bf(v1.x * inv); u1.y = f2bf(v1.y * inv);
  u1.z = f2bf(v1.z * inv); u1.w = f2bf(v1.w * inv);
  ushort* o = outb + (size_t)row * D;
  *(ushort4*)(o + 4 * lane) = u0;
  *(ushort4*)(o + 256 + 4 * lane) = u1;
}

// ---------------------------------------------------------------------------
// MFMA attention — REVERTED to r18-proven kernel (65 us): NPART=16, single
// 256-support pass, acc2 declared only AFTER phase 2 (r19's chunk loop kept
// acc2 live across phase 1 -> accumulator spill to scratch: FETCH_SIZE
// 25->260 MB, attn 65->240 us). 3-deep counted-vmcnt phase-1, exp->bf16
// swizzled P, P @ onehot MFMA epilogue, bf16 partial.
// ---------------------------------------------------------------------------
#define STAGE_BODY(kt, pb)                                                    \
  {                                                                           \
    _Pragma("unroll")                                                         \
    for (int i_ = 0; i_ < 3; i_++) {                                          \
      const int seg_ = wave * 3 + i_;                                         \
      const ushort* src_ = (seg_ < 8)                                         \
          ? Qb + (q0 + seg_ * 16 + fr) * (size_t)D + (kt) * 32 + kg * 8       \
          : Sb + (s0 + (seg_ - 8) * 16 + fr) * (size_t)D + (kt) * 32 + kg * 8;\
      __builtin_amdgcn_global_load_lds(                                       \
          (const __attribute__((address_space(1))) void*)src_,                \
          (__attribute__((address_space(3))) void*)                           \
              &tile[(pb) * 12288 + seg_ * 512 + lane * 8],                    \
          16, 0, 0);                                                          \
    }                                                                         \
  }

__global__ __launch_bounds__(512, 4) void attn_mfma_kernel(
    const ushort* __restrict__ Qb, const ushort* __restrict__ Sb,
    const int* __restrict__ labels, ushort* __restrict__ partial,
    int nq, int D) {
  __shared__ ushort tile[3 * 12288];  // staging rotation; P[128][256] overlays
  __shared__ int lab[256];
  const int tid = threadIdx.x;
  const int wave = tid >> 6, lane = tid & 63;
  const int fr = lane & 15, kg = lane >> 4;
  const int wr = wave >> 2, wc = wave & 3;
  const long q0 = (long)blockIdx.x * 128;
  const int part = blockIdx.y;
  const long s0 = (long)part * 256;

  if (tid < 256) lab[tid] = labels[s0 + tid];

  f32x4 acc[4][4];
#pragma unroll
  for (int rg = 0; rg < 4; rg++)
#pragma unroll
    for (int cg = 0; cg < 4; cg++) acc[rg][cg] = (f32x4){0.f, 0.f, 0.f, 0.f};

  // ---- phase 1: score GEMM, 3-deep counted-vmcnt pipeline ----
  STAGE_BODY(0, 0)
  STAGE_BODY(1, 1)
  int bcur = 0;
  for (int t = 0; t < 16; t++) {
    if (t < 15) asm volatile("s_waitcnt vmcnt(3)" ::: "memory");
    else        asm volatile("s_waitcnt vmcnt(0)" ::: "memory");
    __builtin_amdgcn_sched_barrier(0);
    __builtin_amdgcn_s_barrier();
    if (t < 14) {
      int bnext = bcur + 2; if (bnext >= 3) bnext -= 3;
      STAGE_BODY(t + 2, bnext)
    }
    const ushort* base = &tile[bcur * 12288];
    bf16x8 bfr[4];
#pragma unroll
    for (int cg = 0; cg < 4; cg++)
      bfr[cg] = *(const bf16x8*)&base[(8 + wc * 4 + cg) * 512 + lane * 8];
#pragma unroll
    for (int rg = 0; rg < 4; rg++) {
      bf16x8 af = *(const bf16x8*)&base[(wr * 4 + rg) * 512 + lane * 8];
#pragma unroll
      for (int cg = 0; cg < 4; cg++)
        acc[rg][cg] = __builtin_amdgcn_mfma_f32_16x16x32_bf16(
            af, bfr[cg], acc[rg][cg], 0, 0, 0);
    }
    bcur++; if (bcur == 3) bcur = 0;
  }

  // ---- phase 2: P = exp(S) bf16 -> swizzled LDS ----
  __syncthreads();
#pragma unroll
  for (int rg = 0; rg < 4; rg++)
#pragma unroll
    for (int cg = 0; cg < 4; cg++)
#pragma unroll
      for (int r = 0; r < 4; r++) {
        const int q  = wr * 64 + rg * 16 + kg * 4 + r;
        const int sc = wc * 64 + cg * 16 + fr;
        const int byteoff = ((q << 9) + (sc << 1)) ^ ((q & 7) << 4);
        *(ushort*)((char*)tile + byteoff) = f2bf(__expf(acc[rg][cg][r]));
      }
  __syncthreads();

  // ---- phase 3: out = P @ onehot, K=256 (8 k-steps) ----
  f32x4 acc2[4];
#pragma unroll
  for (int rg = 0; rg < 4; rg++) acc2[rg] = (f32x4){0.f, 0.f, 0.f, 0.f};
  const int cls = wc * 16 + fr;
#pragma unroll
  for (int t = 0; t < 8; t++) {
    const int kb = t * 32 + kg * 8;
    int4 l0 = *(const int4*)&lab[kb];
    int4 l1 = *(const int4*)&lab[kb + 4];
    uint b0 = ((l0.x == cls) ? 0x3F80u : 0u) | (((l0.y == cls) ? 0x3F80u : 0u) << 16);
    uint b1 = ((l0.z == cls) ? 0x3F80u : 0u) | (((l0.w == cls) ? 0x3F80u : 0u) << 16);
    uint b2 = ((l1.x == cls) ? 0x3F80u : 0u) | (((l1.y == cls) ? 0x3F80u : 0u) << 16);
    uint b3 = ((l1.z == cls) ? 0x3F80u : 0u) | (((l1.w == cls) ? 0x3F80u : 0u) << 16);
    uint4 bu = {b0, b1, b2, b3};
    bf16x8 bfr = *(bf16x8*)&bu;
#pragma unroll
    for (int rg = 0; rg < 4; rg++) {
      const int qrow = wr * 64 + rg * 16 + fr;
      const int byteoff = ((qrow << 9) + (kb << 1)) ^ ((qrow & 7) << 4);
      bf16x8 af = *(const bf16x8*)((char*)tile + byteoff);
      acc2[rg] = __builtin_amdgcn_mfma_f32_16x16x32_bf16(af, bfr, acc2[rg], 0, 0, 0);
    }
  }
#pragma unroll
  for (int rg = 0; rg < 4; rg++)
#pragma unroll
    for (int r = 0; r < 4; r++) {
      const long q = q0 + wr * 64 + rg * 16 + kg * 4 + r;
      partial[((size_t)part * nq + q) * 64 + cls] = f2bf(acc2[rg][r]);
    }
}

// ---------------------------------------------------------------------------
__global__ __launch_bounds__(256) void combine_kernel(
    const ushort* __restrict__ partial, float* __restrict__ out, int nq, int nsplit) {
  int q = (int)((blockIdx.x * blockDim.x + threadIdx.x) >> 6);
  int lane = threadIdx.x & 63;
  if (q >= nq) return;
  float v = 0.0f;
  for (int h = 0; h < nsplit; h++)
    v += bf2f(partial[((size_t)h * nq + q) * 64 + lane]);
  float s = v;
#pragma unroll
  for (int off = 32; off > 0; off >>= 1) s += __shfl_xor(s, off);
  out[(size_t)q * 64 + lane] = v / s;
}

// ---------------------------------------------------------------------------
// Workspace: [0,8M) xb_s  [8M,24M) xb_q   (contiguous 12288x1024 bf16)
// [24M,25M) Wt  [25M,33M) s_emb  [33M,49M) q_emb (contiguous 12288x512 f32)
// after encode+norm: s_bf [0,4M), q_bf [4M,12M) (contiguous 12288x512 bf16),
// partial (bf16, 16MB) [12M,28M) — aliases dead xb_q/Wt/s_emb regions.
// All regions rewritten every call; d_out fully overwritten by combine.
// ---------------------------------------------------------------------------
extern "C" void kernel_launch(void* const* d_in, const int* in_sizes, int n_in,
                              void* d_out, int out_size, void* d_ws, size_t ws_size,
                              hipStream_t stream) {
  const float* support = (const float*)d_in[0];
  const float* query   = (const float*)d_in[1];
  const float* W       = (const float*)d_in[2];
  const float* b       = (const float*)d_in[3];
  const int*   labels  = (const int*)d_in[4];

  const int d_dim    = in_sizes[3];            // 512
  const int in_dim   = in_sizes[2] / d_dim;    // 1024
  const int n_support = in_sizes[0] / in_dim;  // 4096
  const int n_query   = in_sizes[1] / in_dim;  // 8192
  const int n_all     = n_support + n_query;   // 12288

  char* base = (char*)d_ws;
  ushort* xb_s  = (ushort*)(base);                        // [0,8M) -- xb base
  ushort* xb_q  = (ushort*)(base + ((size_t)8 << 20));
  ushort* Wt    = (ushort*)(base + ((size_t)24 << 20));
  float*  s_emb = (float*)(base + ((size_t)25 << 20));    // emb base (24M B)
  float*  q_emb = (float*)(base + ((size_t)33 << 20));
  ushort* s_bf  = (ushort*)(base);                        // alias xb_s (dead)
  ushort* q_bf  = (ushort*)(base + ((size_t)4 << 20));    // alias xb (dead)
  ushort* partial = (ushort*)(base + ((size_t)12 << 20)); // alias xb/Wt/s_emb (dead)

  dim3 blk(256);
  cast2_bf16_kernel<<<2048, blk, 0, stream>>>(
      support, xb_s, (size_t)n_support * in_dim / 4,
      query, xb_q, (size_t)n_query * in_dim / 4);
  transpose_cast_kernel<<<dim3(in_dim / 64, d_dim / 64), blk, 0, stream>>>(W, Wt, in_dim, d_dim);
  encode_mfma_kernel<<<dim3(n_all / 128, d_dim / 256), dim3(512), 0, stream>>>(
      xb_s, Wt, b, s_emb, in_dim, d_dim);
  norm_bf16_kernel<<<dim3(n_all / 4), blk, 0, stream>>>(s_emb, s_bf, n_all, d_dim);
  attn_mfma_kernel<<<dim3(n_query / 128, NPART), dim3(512), 0, stream>>>(
      q_bf, s_bf, labels, partial, n_query, d_dim);
  combine_kernel<<<dim3(n_query / 4), blk, 0, stream>>>(partial, (float*)d_out, n_query, NPART);
}

// Round 21
// 114.524 us; speedup vs baseline: 2.5703x; 1.0170x over previous
//
#include <hip/hip_runtime.h>
#include <hip/hip_bf16.h>
#include <math.h>

#define NPART 16  // s-blocks of 256: 64x16 = 1024 blocks (r18-proven)

typedef __attribute__((ext_vector_type(8))) short bf16x8;  // MFMA A/B frag (4 VGPR)
typedef __attribute__((ext_vector_type(4))) float f32x4;   // MFMA C/D frag

static __device__ inline ushort f2bf(float x) {
  __hip_bfloat16 h = __float2bfloat16(x);
  return *reinterpret_cast<ushort*>(&h);
}
static __device__ inline float bf2f(ushort u) {
  uint x = ((uint)u) << 16;
  return *reinterpret_cast<float*>(&x);
}

// ---------------------------------------------------------------------------
// PREP kernel: blocks [0,128) transpose-cast W[1024][512] -> Wt[512][1024]
// bf16 (64x64 LDS tiles); blocks [128, grid) grid-stride cast support+query
// f32 -> bf16. One dispatch replaces two (launch-gap trim); math identical.
// ---------------------------------------------------------------------------
__global__ __launch_bounds__(256) void prep_kernel(
    const float* __restrict__ W, ushort* __restrict__ Wt, int K, int D,
    const float* __restrict__ a, ushort* __restrict__ oa, size_t n4a,
    const float* __restrict__ b, ushort* __restrict__ ob, size_t n4b) {
  __shared__ float t[64][65];
  if (blockIdx.x < 128) {
    const int k0 = (blockIdx.x & 15) * 64, d0 = (blockIdx.x >> 4) * 64;
    const int r = threadIdx.x >> 6, c = threadIdx.x & 63;
#pragma unroll
    for (int i = 0; i < 16; i++)
      t[r + i * 4][c] = W[(size_t)(k0 + r + i * 4) * D + d0 + c];
    __syncthreads();
#pragma unroll
    for (int i = 0; i < 16; i++)
      Wt[(size_t)(d0 + r + i * 4) * K + k0 + c] = f2bf(t[c][r + i * 4]);
  } else {
    size_t i = (size_t)(blockIdx.x - 128) * blockDim.x + threadIdx.x;
    size_t stride = (size_t)(gridDim.x - 128) * blockDim.x;
    for (; i < n4a + n4b; i += stride) {
      const float4* src = (i < n4a) ? &((const float4*)a)[i]
                                    : &((const float4*)b)[i - n4a];
      ushort4* dst = (i < n4a) ? &((ushort4*)oa)[i] : &((ushort4*)ob)[i - n4a];
      float4 v = *src;
      ushort4 u;
      u.x = f2bf(v.x); u.y = f2bf(v.y); u.z = f2bf(v.z); u.w = f2bf(v.w);
      *dst = u;
    }
  }
}

// ---------------------------------------------------------------------------
// FUSED encoder GEMM — r16-proven best config: 512 thr (8 waves 2x4),
// tile 128x256, grid (96,2)=192 blocks, 3-deep counted-vmcnt rotation.
// ---------------------------------------------------------------------------
#define ESTAGE(kt, pb)                                                        \
  {                                                                           \
    _Pragma("unroll")                                                         \
    for (int i_ = 0; i_ < 3; i_++) {                                          \
      const int seg_ = wave * 3 + i_;                                         \
      const ushort* src_ = (seg_ < 8)                                         \
          ? Xall + (row0 + seg_ * 16 + fr) * (size_t)K + (kt) * 32 + kg * 8   \
          : Wt + (d0 + (seg_ - 8) * 16 + fr) * (size_t)K + (kt) * 32 + kg * 8;\
      __builtin_amdgcn_global_load_lds(                                       \
          (const __attribute__((address_space(1))) void*)src_,                \
          (__attribute__((address_space(3))) void*)                           \
              &tile[(pb) * 12288 + seg_ * 512 + lane * 8],                    \
          16, 0, 0);                                                          \
    }                                                                         \
  }

__global__ __launch_bounds__(512, 4) void encode_mfma_kernel(
    const ushort* __restrict__ Xall, const ushort* __restrict__ Wt,
    const float* __restrict__ bias, float* __restrict__ emb,
    int K, int D) {
  __shared__ ushort tile[3 * 12288];   // 72 KB, 3-deep rotation
  const int tid = threadIdx.x;
  const int wave = tid >> 6, lane = tid & 63;
  const int fr = lane & 15, kg = lane >> 4;
  const int wr = wave >> 2, wc = wave & 3;
  const long row0 = (long)blockIdx.x * 128;
  const int d0 = blockIdx.y * 256;

  f32x4 acc[4][4];
#pragma unroll
  for (int rg = 0; rg < 4; rg++)
#pragma unroll
    for (int cg = 0; cg < 4; cg++) acc[rg][cg] = (f32x4){0.f, 0.f, 0.f, 0.f};

  ESTAGE(0, 0)
  ESTAGE(1, 1)
  int bcur = 0;
  for (int t = 0; t < 32; t++) {     // K = 1024 = 32 x BK(32)
    if (t < 31) asm volatile("s_waitcnt vmcnt(3)" ::: "memory");
    else        asm volatile("s_waitcnt vmcnt(0)" ::: "memory");
    __builtin_amdgcn_sched_barrier(0);
    __builtin_amdgcn_s_barrier();
    if (t < 30) {
      int bnext = bcur + 2; if (bnext >= 3) bnext -= 3;
      ESTAGE(t + 2, bnext)
    }
    const ushort* base = &tile[bcur * 12288];
    bf16x8 bfr[4];
#pragma unroll
    for (int cg = 0; cg < 4; cg++)
      bfr[cg] = *(const bf16x8*)&base[(8 + wc * 4 + cg) * 512 + lane * 8];
#pragma unroll
    for (int rg = 0; rg < 4; rg++) {
      bf16x8 af = *(const bf16x8*)&base[(wr * 4 + rg) * 512 + lane * 8];
#pragma unroll
      for (int cg = 0; cg < 4; cg++)
        acc[rg][cg] = __builtin_amdgcn_mfma_f32_16x16x32_bf16(
            af, bfr[cg], acc[rg][cg], 0, 0, 0);
    }
    bcur++; if (bcur == 3) bcur = 0;
  }
#pragma unroll
  for (int cg = 0; cg < 4; cg++) {
    const int col = d0 + wc * 64 + cg * 16 + fr;
    const float bl = bias[col];
#pragma unroll
    for (int rg = 0; rg < 4; rg++)
#pragma unroll
      for (int r = 0; r < 4; r++)
        emb[(row0 + wr * 64 + rg * 16 + kg * 4 + r) * (size_t)D + col] =
            acc[rg][cg][r] + bl;
  }
}

// ---------------------------------------------------------------------------
__global__ __launch_bounds__(256) void norm_bf16_kernel(
    const float* __restrict__ in, ushort* __restrict__ outb, int nrows, int D) {
  int row = (int)((blockIdx.x * blockDim.x + threadIdx.x) >> 6);
  int lane = threadIdx.x & 63;
  if (row >= nrows) return;
  const float4* p = (const float4*)(in + (size_t)row * D);
  float4 v0 = p[lane];
  float4 v1 = p[lane + 64];
  float ss = v0.x * v0.x + v0.y * v0.y + v0.z * v0.z + v0.w * v0.w
           + v1.x * v1.x + v1.y * v1.y + v1.z * v1.z + v1.w * v1.w;
#pragma unroll
  for (int off = 32; off > 0; off >>= 1) ss += __shfl_xor(ss, off);
  float inv = 1.0f / fmaxf(sqrtf(ss), 1e-12f);
  ushort4 u0, u1;
  u0.x = f2bf(v0.x * inv); u0.y = f2bf(v0.y * inv);
  u0.z = f2bf(v0.z * inv); u0.w = f2bf(v0.w * inv);
  u1.x = f2bf(v1.x * inv); u1.y = f2bf(v1.y * inv);
  u1.z = f2bf(v1.z * inv); u1.w = f2bf(v1.w * inv);
  ushort* o = outb + (size_t)row * D;
  *(ushort4*)(o + 4 * lane) = u0;
  *(ushort4*)(o + 256 + 4 * lane) = u1;
}

// ---------------------------------------------------------------------------
// MFMA attention — r18/r20-proven kernel, unchanged: NPART=16, 3-deep
// counted-vmcnt phase-1, exp->bf16 swizzled P, P @ onehot MFMA, bf16 partial.
// (acc2 declared only after phase 2 — r19's chunk loop spilled accumulators.)
// ---------------------------------------------------------------------------
#define STAGE_BODY(kt, pb)                                                    \
  {                                                                           \
    _Pragma("unroll")                                                         \
    for (int i_ = 0; i_ < 3; i_++) {                                          \
      const int seg_ = wave * 3 + i_;                                         \
      const ushort* src_ = (seg_ < 8)                                         \
          ? Qb + (q0 + seg_ * 16 + fr) * (size_t)D + (kt) * 32 + kg * 8       \
          : Sb + (s0 + (seg_ - 8) * 16 + fr) * (size_t)D + (kt) * 32 + kg * 8;\
      __builtin_amdgcn_global_load_lds(                                       \
          (const __attribute__((address_space(1))) void*)src_,                \
          (__attribute__((address_space(3))) void*)                           \
              &tile[(pb) * 12288 + seg_ * 512 + lane * 8],                    \
          16, 0, 0);                                                          \
    }                                                                         \
  }

__global__ __launch_bounds__(512, 4) void attn_mfma_kernel(
    const ushort* __restrict__ Qb, const ushort* __restrict__ Sb,
    const int* __restrict__ labels, ushort* __restrict__ partial,
    int nq, int D) {
  __shared__ ushort tile[3 * 12288];  // staging rotation; P[128][256] overlays
  __shared__ int lab[256];
  const int tid = threadIdx.x;
  const int wave = tid >> 6, lane = tid & 63;
  const int fr = lane & 15, kg = lane >> 4;
  const int wr = wave >> 2, wc = wave & 3;
  const long q0 = (long)blockIdx.x * 128;
  const int part = blockIdx.y;
  const long s0 = (long)part * 256;

  if (tid < 256) lab[tid] = labels[s0 + tid];

  f32x4 acc[4][4];
#pragma unroll
  for (int rg = 0; rg < 4; rg++)
#pragma unroll
    for (int cg = 0; cg < 4; cg++) acc[rg][cg] = (f32x4){0.f, 0.f, 0.f, 0.f};

  // ---- phase 1: score GEMM, 3-deep counted-vmcnt pipeline ----
  STAGE_BODY(0, 0)
  STAGE_BODY(1, 1)
  int bcur = 0;
  for (int t = 0; t < 16; t++) {
    if (t < 15) asm volatile("s_waitcnt vmcnt(3)" ::: "memory");
    else        asm volatile("s_waitcnt vmcnt(0)" ::: "memory");
    __builtin_amdgcn_sched_barrier(0);
    __builtin_amdgcn_s_barrier();
    if (t < 14) {
      int bnext = bcur + 2; if (bnext >= 3) bnext -= 3;
      STAGE_BODY(t + 2, bnext)
    }
    const ushort* base = &tile[bcur * 12288];
    bf16x8 bfr[4];
#pragma unroll
    for (int cg = 0; cg < 4; cg++)
      bfr[cg] = *(const bf16x8*)&base[(8 + wc * 4 + cg) * 512 + lane * 8];
#pragma unroll
    for (int rg = 0; rg < 4; rg++) {
      bf16x8 af = *(const bf16x8*)&base[(wr * 4 + rg) * 512 + lane * 8];
#pragma unroll
      for (int cg = 0; cg < 4; cg++)
        acc[rg][cg] = __builtin_amdgcn_mfma_f32_16x16x32_bf16(
            af, bfr[cg], acc[rg][cg], 0, 0, 0);
    }
    bcur++; if (bcur == 3) bcur = 0;
  }

  // ---- phase 2: P = exp(S) bf16 -> swizzled LDS ----
  __syncthreads();
#pragma unroll
  for (int rg = 0; rg < 4; rg++)
#pragma unroll
    for (int cg = 0; cg < 4; cg++)
#pragma unroll
      for (int r = 0; r < 4; r++) {
        const int q  = wr * 64 + rg * 16 + kg * 4 + r;
        const int sc = wc * 64 + cg * 16 + fr;
        const int byteoff = ((q << 9) + (sc << 1)) ^ ((q & 7) << 4);
        *(ushort*)((char*)tile + byteoff) = f2bf(__expf(acc[rg][cg][r]));
      }
  __syncthreads();

  // ---- phase 3: out = P @ onehot, K=256 (8 k-steps) ----
  f32x4 acc2[4];
#pragma unroll
  for (int rg = 0; rg < 4; rg++) acc2[rg] = (f32x4){0.f, 0.f, 0.f, 0.f};
  const int cls = wc * 16 + fr;
#pragma unroll
  for (int t = 0; t < 8; t++) {
    const int kb = t * 32 + kg * 8;
    int4 l0 = *(const int4*)&lab[kb];
    int4 l1 = *(const int4*)&lab[kb + 4];
    uint b0 = ((l0.x == cls) ? 0x3F80u : 0u) | (((l0.y == cls) ? 0x3F80u : 0u) << 16);
    uint b1 = ((l0.z == cls) ? 0x3F80u : 0u) | (((l0.w == cls) ? 0x3F80u : 0u) << 16);
    uint b2 = ((l1.x == cls) ? 0x3F80u : 0u) | (((l1.y == cls) ? 0x3F80u : 0u) << 16);
    uint b3 = ((l1.z == cls) ? 0x3F80u : 0u) | (((l1.w == cls) ? 0x3F80u : 0u) << 16);
    uint4 bu = {b0, b1, b2, b3};
    bf16x8 bfr = *(bf16x8*)&bu;
#pragma unroll
    for (int rg = 0; rg < 4; rg++) {
      const int qrow = wr * 64 + rg * 16 + fr;
      const int byteoff = ((qrow << 9) + (kb << 1)) ^ ((qrow & 7) << 4);
      bf16x8 af = *(const bf16x8*)((char*)tile + byteoff);
      acc2[rg] = __builtin_amdgcn_mfma_f32_16x16x32_bf16(af, bfr, acc2[rg], 0, 0, 0);
    }
  }
#pragma unroll
  for (int rg = 0; rg < 4; rg++)
#pragma unroll
    for (int r = 0; r < 4; r++) {
      const long q = q0 + wr * 64 + rg * 16 + kg * 4 + r;
      partial[((size_t)part * nq + q) * 64 + cls] = f2bf(acc2[rg][r]);
    }
}

// ---------------------------------------------------------------------------
__global__ __launch_bounds__(256) void combine_kernel(
    const ushort* __restrict__ partial, float* __restrict__ out, int nq, int nsplit) {
  int q = (int)((blockIdx.x * blockDim.x + threadIdx.x) >> 6);
  int lane = threadIdx.x & 63;
  if (q >= nq) return;
  float v = 0.0f;
  for (int h = 0; h < nsplit; h++)
    v += bf2f(partial[((size_t)h * nq + q) * 64 + lane]);
  float s = v;
#pragma unroll
  for (int off = 32; off > 0; off >>= 1) s += __shfl_xor(s, off);
  out[(size_t)q * 64 + lane] = v / s;
}

// ---------------------------------------------------------------------------
// Workspace: [0,8M) xb_s  [8M,24M) xb_q   (contiguous 12288x1024 bf16)
// [24M,25M) Wt  [25M,33M) s_emb  [33M,49M) q_emb (contiguous 12288x512 f32)
// after encode+norm: s_bf [0,4M), q_bf [4M,12M) (contiguous 12288x512 bf16),
// partial (bf16, 16MB) [12M,28M) — aliases dead xb_q/Wt/s_emb regions.
// All regions rewritten every call; d_out fully overwritten by combine.
// ---------------------------------------------------------------------------
extern "C" void kernel_launch(void* const* d_in, const int* in_sizes, int n_in,
                              void* d_out, int out_size, void* d_ws, size_t ws_size,
                              hipStream_t stream) {
  const float* support = (const float*)d_in[0];
  const float* query   = (const float*)d_in[1];
  const float* W       = (const float*)d_in[2];
  const float* b       = (const float*)d_in[3];
  const int*   labels  = (const int*)d_in[4];

  const int d_dim    = in_sizes[3];            // 512
  const int in_dim   = in_sizes[2] / d_dim;    // 1024
  const int n_support = in_sizes[0] / in_dim;  // 4096
  const int n_query   = in_sizes[1] / in_dim;  // 8192
  const int n_all     = n_support + n_query;   // 12288

  char* base = (char*)d_ws;
  ushort* xb_s  = (ushort*)(base);                        // [0,8M) -- xb base
  ushort* xb_q  = (ushort*)(base + ((size_t)8 << 20));
  ushort* Wt    = (ushort*)(base + ((size_t)24 << 20));
  float*  s_emb = (float*)(base + ((size_t)25 << 20));    // emb base (24M B)
  float*  q_emb = (float*)(base + ((size_t)33 << 20));
  ushort* s_bf  = (ushort*)(base);                        // alias xb_s (dead)
  ushort* q_bf  = (ushort*)(base + ((size_t)4 << 20));    // alias xb (dead)
  ushort* partial = (ushort*)(base + ((size_t)12 << 20)); // alias xb/Wt/s_emb (dead)

  dim3 blk(256);
  prep_kernel<<<2176, blk, 0, stream>>>(
      W, Wt, in_dim, d_dim,
      support, xb_s, (size_t)n_support * in_dim / 4,
      query, xb_q, (size_t)n_query * in_dim / 4);
  encode_mfma_kernel<<<dim3(n_all / 128, d_dim / 256), dim3(512), 0, stream>>>(
      xb_s, Wt, b, s_emb, in_dim, d_dim);
  norm_bf16_kernel<<<dim3(n_all / 4), blk, 0, stream>>>(s_emb, s_bf, n_all, d_dim);
  attn_mfma_kernel<<<dim3(n_query / 128, NPART), dim3(512), 0, stream>>>(
      q_bf, s_bf, labels, partial, n_query, d_dim);
  combine_kernel<<<dim3(n_query / 4), blk, 0, stream>>>(partial, (float*)d_out, n_query, NPART);
}